// Round 5
// baseline (182.265 us; speedup 1.0000x reference)
//
#include <hip/hip_runtime.h>
#include <math.h>

#define NPTS   8192
#define DDIM   128
#define NBLK   64            // 8192 / 128 row-blocks
#define NTRI   2080          // NBLK*(NBLK+1)/2 working blocks

using short8 = __attribute__((ext_vector_type(8))) short;
using f32x4  = __attribute__((ext_vector_type(4))) float;

__device__ __forceinline__ unsigned short f2bf(float f) {
    unsigned int u = __float_as_uint(f);
    u += 0x7fffu + ((u >> 16) & 1u);
    return (unsigned short)(u >> 16);
}
__device__ __forceinline__ float bf2f(unsigned short s) {
    return __uint_as_float(((unsigned int)s) << 16);
}

// --- kernel 1: bf16 convert + sq (bf16-consistent) + exact fp32 class stats ---
// one wave per row; lane handles 2 consecutive floats
__global__ __launch_bounds__(256) void prep_kernel(
    const float* __restrict__ X, const int* __restrict__ lab,
    unsigned short* __restrict__ Xbf, float* __restrict__ sq,
    float* __restrict__ clsSum, float* __restrict__ clsSq,
    int* __restrict__ clsCnt)
{
    const int wave = threadIdx.x >> 6, lane = threadIdx.x & 63;
    const int row  = blockIdx.x * 4 + wave;
    const int c    = lab[row];

    float2 v = *(const float2*)(X + (size_t)row * DDIM + lane * 2);
    unsigned short a = f2bf(v.x), b = f2bf(v.y);
    float fa = bf2f(a), fb = bf2f(b);
    float s_bf = fa * fa + fb * fb;          // bf16-rounded (matches MFMA Gram)
    float s_fp = v.x * v.x + v.y * v.y;      // exact fp32 (analytic pos term)
    *(ushort2*)(Xbf + (size_t)row * DDIM + lane * 2) = make_ushort2(a, b);

    // exact class vector sums (pos term is analytic: no Gram needed for it)
    atomicAdd(&clsSum[c * DDIM + lane * 2],     v.x);
    atomicAdd(&clsSum[c * DDIM + lane * 2 + 1], v.y);

#pragma unroll
    for (int off = 32; off > 0; off >>= 1) {
        s_bf += __shfl_down(s_bf, off);
        s_fp += __shfl_down(s_fp, off);
    }
    if (lane == 0) {
        sq[row] = s_bf;
        atomicAdd(&clsSq[c], s_fp);
        atomicAdd(clsCnt + c, 1);
    }
}

// --- kernel 2: barrier-free Gram tiles; hinge-only epilogue; fused finalize ---
__global__ __launch_bounds__(256, 2) void pair_kernel(
    const unsigned short* __restrict__ Xbf, const int* __restrict__ lab,
    const float* __restrict__ sq, float* __restrict__ slots,
    const float* __restrict__ clsSum, const float* __restrict__ clsSq,
    const int* __restrict__ clsCnt, unsigned int* __restrict__ counter,
    float* __restrict__ out)
{
    const int k = blockIdx.x;
    int bi = (int)((129.0f - sqrtf((float)(16641 - 8 * k))) * 0.5f);
    if (bi < 0) bi = 0;
    while (64 * (bi + 1) - ((bi + 1) * bi) / 2 <= k) ++bi;
    while (64 * bi - (bi * (bi - 1)) / 2 > k) --bi;
    const int bj = bi + (k - (64 * bi - (bi * (bi - 1)) / 2));

    __shared__ float sSqA[128], sSqB[128];
    __shared__ int   sLabA[128], sLabB[128];
    __shared__ float rN[4];
    __shared__ int   sIsLast;

    const int tid   = threadIdx.x;
    const int rowA0 = bi * 128;
    const int rowB0 = bj * 128;

    if (tid < 128) {
        sSqA[tid]  = sq[rowA0 + tid];
        sLabA[tid] = lab[rowA0 + tid];
    } else {
        int t = tid - 128;
        sSqB[t]  = sq[rowB0 + t];
        sLabB[t] = lab[rowB0 + t];
    }

    const int wave = tid >> 6, lane = tid & 63;
    const int quad = lane >> 4, rr = lane & 15;
    const int wr = wave >> 1, wc = wave & 1;

    // A fragment for 16x16x32: row = lane&15, k = (lane>>4)*8 + j -> 16B contiguous
    const unsigned short* pA = Xbf + (size_t)(rowA0 + wr * 64 + rr) * DDIM + quad * 8;
    const unsigned short* pB = Xbf + (size_t)(rowB0 + wc * 64 + rr) * DDIM + quad * 8;

    // hoist ALL fragment loads: 32 x 16B in flight per wave (one latency exposure)
    short8 a[4][4], b[4][4];   // [t][kc]
#pragma unroll
    for (int kc = 0; kc < 4; ++kc) {
#pragma unroll
        for (int t = 0; t < 4; ++t) {
            a[t][kc] = *(const short8*)(pA + t * 16 * DDIM + kc * 32);
            b[t][kc] = *(const short8*)(pB + t * 16 * DDIM + kc * 32);
        }
    }

    f32x4 acc[4][4];
#pragma unroll
    for (int i = 0; i < 4; ++i)
#pragma unroll
        for (int j = 0; j < 4; ++j)
            acc[i][j] = (f32x4){0.f, 0.f, 0.f, 0.f};

#pragma unroll
    for (int kc = 0; kc < 4; ++kc)
#pragma unroll
        for (int i = 0; i < 4; ++i)
#pragma unroll
            for (int j = 0; j < 4; ++j)
                acc[i][j] = __builtin_amdgcn_mfma_f32_16x16x32_bf16(a[i][kc], b[j][kc], acc[i][j], 0, 0, 0);

    __syncthreads();   // publish sq/lab (overlapped with MFMA above)

    // epilogue. C/D: col = lane&15, row = quad*4 + reg (verified)
    float sb[4];
#pragma unroll
    for (int j = 0; j < 4; ++j) sb[j] = sSqB[wc * 64 + j * 16 + rr];

    // fast path: min over ALL unclamped d' (d_clamped<4 <=> d'<4); no label work
    float dmin = 1e30f;
#pragma unroll
    for (int i = 0; i < 4; ++i) {
        float sa4[4];
#pragma unroll
        for (int rg = 0; rg < 4; ++rg) sa4[rg] = sSqA[wr * 64 + i * 16 + quad * 4 + rg];
#pragma unroll
        for (int rg = 0; rg < 4; ++rg)
#pragma unroll
            for (int j = 0; j < 4; ++j)
                dmin = fminf(dmin, sa4[rg] + sb[j] - 2.0f * acc[i][j][rg]);
    }

    float negS = 0.f;
    if (__any(dmin < 4.0f)) {   // diagonal blocks (i==j pairs) and any true hinge hits
        int lb[4];
#pragma unroll
        for (int j = 0; j < 4; ++j) lb[j] = sLabB[wc * 64 + j * 16 + rr];
#pragma unroll
        for (int i = 0; i < 4; ++i) {
#pragma unroll
            for (int rg = 0; rg < 4; ++rg) {
                int   rl = wr * 64 + i * 16 + quad * 4 + rg;
                float sa = sSqA[rl];
                int   la = sLabA[rl];
#pragma unroll
                for (int j = 0; j < 4; ++j) {
                    float d = fmaxf(sa + sb[j] - 2.0f * acc[i][j][rg], 0.0f);
                    float t = fmaxf(2.0f - sqrtf(d + 1e-9f), 0.f);
                    negS += (la == lb[j]) ? 0.f : t * t;
                }
            }
        }
    }

    negS *= (bi == bj) ? 1.0f : 2.0f;
#pragma unroll
    for (int off = 32; off > 0; off >>= 1) negS += __shfl_down(negS, off);
    if (lane == 0) rN[wave] = negS;
    __syncthreads();
    if (tid == 0) {
        slots[k] = rN[0] + rN[1] + rN[2] + rN[3];
        __threadfence();                           // release slots before counting
        unsigned int old = atomicAdd(counter, 1);
        sIsLast = (old == NTRI - 1);
    }
    __syncthreads();
    if (!sIsLast) return;

    // ---- last block: final reduction + analytic pos term ----
    __threadfence();   // acquire: all slots visible
    float nsum = 0.f;
    for (int i = tid; i < NTRI; i += 256) nsum += slots[i];
#pragma unroll
    for (int off = 32; off > 0; off >>= 1) nsum += __shfl_down(nsum, off);
    __syncthreads();                 // rN reuse: previous reads done
    if (lane == 0) rN[wave] = nsum;
    __syncthreads();

    float pp = 0.f, np = 0.f;
    if (tid < 64) {
        float s2 = 0.f;
        for (int d = 0; d < DDIM; ++d) {
            float v = clsSum[tid * DDIM + d];
            s2 = fmaf(v, v, s2);
        }
        float nc = (float)clsCnt[tid];
        pp = nc * clsSq[tid] - s2;   // n_c * sum||x||^2 - ||sum x||^2
        np = nc * nc;
    }
#pragma unroll
    for (int off = 32; off > 0; off >>= 1) {
        pp += __shfl_down(pp, off);
        np += __shfl_down(np, off);
    }
    if (tid == 0) {
        float  negTotal = rN[0] + rN[1] + rN[2] + rN[3];
        double dist_pos = 2.0 * (double)pp;
        double num_pos  = (double)np;
        double num_neg  = (double)NPTS * (double)NPTS - num_pos;
        double pos_t = (num_pos > 0.0) ? 0.5 * dist_pos / num_pos : 0.0;
        double neg_t = (num_neg > 0.0) ? 0.5 * (double)negTotal / num_neg : 0.0;
        out[0] = (float)(pos_t + neg_t);
    }
}

extern "C" void kernel_launch(void* const* d_in, const int* in_sizes, int n_in,
                              void* d_out, int out_size, void* d_ws, size_t ws_size,
                              hipStream_t stream) {
    const float* X   = (const float*)d_in[0];
    const int*   lab = (const int*)d_in[1];
    float*       out = (float*)d_out;

    char* ws = (char*)d_ws;
    unsigned int*   counter = (unsigned int*)(ws + 0);
    int*            clsCnt  = (int*)(ws + 256);            // int[64]
    float*          clsSq   = (float*)(ws + 1024);         // float[64]
    float*          clsSum  = (float*)(ws + 4096);         // float[64*128] = 32 KB
    float*          slots   = (float*)(ws + 64 * 1024);    // float[NTRI]
    float*          sq      = (float*)(ws + 80 * 1024);    // float[8192] = 32 KB
    unsigned short* Xbf     = (unsigned short*)(ws + 128 * 1024); // 2 MB

    hipMemsetAsync(ws, 0, 64 * 1024, stream);  // counter + class stats
    prep_kernel<<<NPTS / 4, 256, 0, stream>>>(X, lab, Xbf, sq, clsSum, clsSq, clsCnt);
    pair_kernel<<<NTRI, 256, 0, stream>>>(Xbf, lab, sq, slots, clsSum, clsSq, clsCnt, counter, out);
}

// Round 6
// 117.354 us; speedup vs baseline: 1.5531x; 1.5531x over previous
//
#include <hip/hip_runtime.h>
#include <math.h>

#define NPTS   8192
#define DDIM   128
#define NT2    16512   // wave-tiles: 256 row-blocks(32) x cols 64-blocks, cb >= rb/2

using short8 = __attribute__((ext_vector_type(8))) short;
using f32x4  = __attribute__((ext_vector_type(4))) float;

__device__ __forceinline__ unsigned short f2bf(float f) {
    unsigned int u = __float_as_uint(f);
    u += 0x7fffu + ((u >> 16) & 1u);
    return (unsigned short)(u >> 16);
}
__device__ __forceinline__ float bf2f(unsigned short s) {
    return __uint_as_float(((unsigned int)s) << 16);
}

// cumulative tile count before row-block rb: C(rb) = 128*rb - (rb^2-2rb+(rb&1))/4
__device__ __forceinline__ int Cof(int r) {
    return 128 * r - ((r * r - 2 * r + (r & 1)) >> 2);
}

// --- kernel 1: convert X -> bf16 once; sq[i] = ||bf16(x_i)||^2 ---
__global__ __launch_bounds__(256) void prep_kernel(
    const float* __restrict__ X, unsigned short* __restrict__ Xbf,
    float* __restrict__ sq)
{
    const int wave = threadIdx.x >> 6, lane = threadIdx.x & 63;
    const int row  = blockIdx.x * 4 + wave;
    float2 v = *(const float2*)(X + (size_t)row * DDIM + lane * 2);
    unsigned short a = f2bf(v.x), b = f2bf(v.y);
    float fa = bf2f(a), fb = bf2f(b);
    float s = fa * fa + fb * fb;
    *(ushort2*)(Xbf + (size_t)row * DDIM + lane * 2) = make_ushort2(a, b);
#pragma unroll
    for (int off = 32; off > 0; off >>= 1) s += __shfl_down(s, off);
    if (lane == 0) sq[row] = s;
}

// --- kernel 2: independent 32x64 wave-tiles; no LDS, no barriers, no atomics ---
// R4-style kc-interleaved loads (hoisting regressed in R5); occupancy via
// launch_bounds(256,4): acc=32 regs -> ~96 live, 4+ waves/SIMD.
__global__ __launch_bounds__(256, 4) void pair_kernel(
    const unsigned short* __restrict__ Xbf, const int* __restrict__ lab,
    const float* __restrict__ sq, float* __restrict__ slots /* [2][NT2] */)
{
    const int wave = threadIdx.x >> 6, lane = threadIdx.x & 63;
    const int t = blockIdx.x * 4 + wave;           // grid*4 == NT2 exactly

    // decode flat tile id -> (rb, cb): rows [rb*32,+32), cols [cb*64,+64)
    float s0 = sqrtf(264196.0f - 16.0f * (float)t);
    int rb = (int)((514.0f - s0) * 0.5f);
    if (rb < 0) rb = 0;
    if (rb > 255) rb = 255;
    while (Cof(rb + 1) <= t) ++rb;
    while (Cof(rb) > t) --rb;
    const int cb = (rb >> 1) + (t - Cof(rb));
    const bool overlap = (cb == (rb >> 1));        // tile touches the diagonal

    const int quad = lane >> 4, rr = lane & 15;
    const int row0 = rb * 32, col0 = cb * 64;

    // fragment bases: A[m=rr][k=quad*8+..] is 16B contiguous in row-major Xbf
    const unsigned short* pA = Xbf + (size_t)(row0 + rr) * DDIM + quad * 8;
    const unsigned short* pB = Xbf + (size_t)(col0 + rr) * DDIM + quad * 8;

    f32x4 acc[2][4];
#pragma unroll
    for (int i = 0; i < 2; ++i)
#pragma unroll
        for (int j = 0; j < 4; ++j)
            acc[i][j] = (f32x4){0.f, 0.f, 0.f, 0.f};

#pragma unroll
    for (int kc = 0; kc < 4; ++kc) {               // K=128 in 4 chunks of 32
        short8 a[2], b[4];
#pragma unroll
        for (int i = 0; i < 2; ++i)
            a[i] = *(const short8*)(pA + i * 16 * DDIM + kc * 32);
#pragma unroll
        for (int j = 0; j < 4; ++j)
            b[j] = *(const short8*)(pB + j * 16 * DDIM + kc * 32);
#pragma unroll
        for (int i = 0; i < 2; ++i)
#pragma unroll
            for (int j = 0; j < 4; ++j)
                acc[i][j] = __builtin_amdgcn_mfma_f32_16x16x32_bf16(a[i], b[j], acc[i][j], 0, 0, 0);
    }

    // epilogue. C/D layout: col = lane&15, row = quad*4 + reg (verified)
    // sq/lab gathers hit tiny L1-resident ranges
    float sb[4]; int lb[4];
#pragma unroll
    for (int j = 0; j < 4; ++j) {
        int cl = col0 + j * 16 + rr;
        sb[j] = sq[cl];
        lb[j] = lab[cl];
    }
    float sa[2][4]; int la[2][4];
#pragma unroll
    for (int i = 0; i < 2; ++i)
#pragma unroll
        for (int rg = 0; rg < 4; ++rg) {
            int rl = row0 + i * 16 + quad * 4 + rg;
            sa[i][rg] = sq[rl];
            la[i][rg] = lab[rl];
        }

    float posS = 0.f, dmin = 1e30f;
#pragma unroll
    for (int i = 0; i < 2; ++i) {
#pragma unroll
        for (int rg = 0; rg < 4; ++rg) {
            int rl = row0 + i * 16 + quad * 4 + rg;
#pragma unroll
            for (int j = 0; j < 4; ++j) {
                int   cl = col0 + j * 16 + rr;
                bool  ok = !overlap || (cl > rl);  // strict upper triangle
                float d0 = sa[i][rg] + sb[j] - 2.0f * acc[i][j][rg]; // unclamped
                bool  same = (la[i][rg] == lb[j]);
                posS += (ok && same) ? fmaxf(d0, 0.f) : 0.f;
                dmin = fminf(dmin, (ok && !same) ? d0 : 1e30f);
            }
        }
    }

    float negS = 0.f;
    if (__any(dmin < 4.0f)) {   // hinge active (d0<0 clamps to 0 -> also <4)
#pragma unroll
        for (int i = 0; i < 2; ++i) {
#pragma unroll
            for (int rg = 0; rg < 4; ++rg) {
                int rl = row0 + i * 16 + quad * 4 + rg;
#pragma unroll
                for (int j = 0; j < 4; ++j) {
                    int   cl = col0 + j * 16 + rr;
                    bool  ok = !overlap || (cl > rl);
                    float d = fmaxf(sa[i][rg] + sb[j] - 2.0f * acc[i][j][rg], 0.f);
                    float h = fmaxf(2.0f - sqrtf(d + 1e-9f), 0.f);
                    negS += (ok && (la[i][rg] != lb[j])) ? h * h : 0.f;
                }
            }
        }
    }

#pragma unroll
    for (int off = 32; off > 0; off >>= 1) {
        posS += __shfl_down(posS, off);
        negS += __shfl_down(negS, off);
    }
    if (lane == 0) {
        slots[t]       = posS;   // sums over unordered pairs (i<j)
        slots[NT2 + t] = negS;
    }
}

// --- kernel 3: histogram (exact num_pos) + slot reduce + combine ---
__global__ __launch_bounds__(1024) void finalize_kernel(
    const float* __restrict__ slots, const int* __restrict__ lab,
    float* __restrict__ out)
{
    __shared__ int   hist[64];
    __shared__ float sP[16], sN[16];
    const int tid = threadIdx.x;
    if (tid < 64) hist[tid] = 0;
    __syncthreads();
    for (int i = tid; i < NPTS; i += 1024) atomicAdd(&hist[lab[i]], 1);

    float p = 0.f, n = 0.f;
    for (int i = tid; i < NT2; i += 1024) { p += slots[i]; n += slots[NT2 + i]; }
#pragma unroll
    for (int off = 32; off > 0; off >>= 1) {
        p += __shfl_down(p, off);
        n += __shfl_down(n, off);
    }
    const int wave = tid >> 6, lane = tid & 63;
    if (lane == 0) { sP[wave] = p; sN[wave] = n; }
    __syncthreads();
    if (tid == 0) {
        long long np = 0;
        for (int c = 0; c < 64; ++c) np += (long long)hist[c] * hist[c];
        float tp = 0.f, tn = 0.f;
#pragma unroll
        for (int w = 0; w < 16; ++w) { tp += sP[w]; tn += sN[w]; }
        // ordered sums = 2 * unordered (diagonal contributes 0 to both terms)
        double num_pos = (double)np;
        double num_neg = (double)NPTS * (double)NPTS - num_pos;
        double pos_t = (num_pos > 0.0) ? (double)tp / num_pos : 0.0;
        double neg_t = (num_neg > 0.0) ? (double)tn / num_neg : 0.0;
        out[0] = (float)(pos_t + neg_t);
    }
}

extern "C" void kernel_launch(void* const* d_in, const int* in_sizes, int n_in,
                              void* d_out, int out_size, void* d_ws, size_t ws_size,
                              hipStream_t stream) {
    const float* X   = (const float*)d_in[0];
    const int*   lab = (const int*)d_in[1];
    float*       out = (float*)d_out;

    char* ws = (char*)d_ws;
    float*          slots = (float*)(ws);                    // 2*16512 floats = 132 KB
    float*          sq    = (float*)(ws + 160 * 1024);       // 32 KB
    unsigned short* Xbf   = (unsigned short*)(ws + 256 * 1024); // 2 MB

    prep_kernel<<<NPTS / 4, 256, 0, stream>>>(X, Xbf, sq);
    pair_kernel<<<NT2 / 4, 256, 0, stream>>>(Xbf, lab, sq, slots);
    finalize_kernel<<<1, 1024, 0, stream>>>(slots, lab, out);
}